// Round 4
// baseline (960.721 us; speedup 1.0000x reference)
//
#include <hip/hip_runtime.h>
#include <cstdint>

static constexpr int N = 20000;
static constexpr int E = 320000;
static constexpr int R = 8;
static constexpr int H = 4;
static constexpr int C = 256;

using short8 = __attribute__((ext_vector_type(8))) short;
using f32x4  = __attribute__((ext_vector_type(4))) float;

__device__ __forceinline__ float lrelu(float x, float s) { return x >= 0.f ? x : s * x; }
__device__ __forceinline__ unsigned short f2bf(float f) {
    unsigned u = __float_as_uint(f);
    unsigned r = (u + 0x7FFFu + ((u >> 16) & 1u)) >> 16;
    return (unsigned short)r;
}

// ---------------- CSR build ----------------
__global__ void k_zero_int(int* p, int n) {
    int i = blockIdx.x * blockDim.x + threadIdx.x;
    if (i < n) p[i] = 0;
}

__global__ void k_count(const int* __restrict__ ei, int* __restrict__ cnt) {
    int e = blockIdx.x * blockDim.x + threadIdx.x;
    if (e < E) atomicAdd(&cnt[ei[E + e]], 1);
}

__global__ __launch_bounds__(1024) void k_scan(const int* __restrict__ cnt,
                                               int* __restrict__ rowptr) {
    __shared__ int part[1024];
    const int CH = (N + 1023) / 1024;  // 20
    int t = threadIdx.x;
    int base = t * CH;
    int sum = 0;
    for (int j = 0; j < CH; ++j) {
        int idx = base + j;
        if (idx < N) sum += cnt[idx];
    }
    part[t] = sum;
    __syncthreads();
    for (int off = 1; off < 1024; off <<= 1) {
        int v = 0;
        if (t >= off) v = part[t - off];
        __syncthreads();
        if (t >= off) part[t] += v;
        __syncthreads();
    }
    int run = part[t] - sum;
    for (int j = 0; j < CH; ++j) {
        int idx = base + j;
        if (idx < N) { rowptr[idx] = run; run += cnt[idx]; }
    }
    if (t == 1023) rowptr[N] = part[1023];
}

__global__ void k_dis(const int* __restrict__ cnt, float* __restrict__ dis) {
    int i = blockIdx.x * blockDim.x + threadIdx.x;
    if (i < N) dis[i] = rsqrtf((float)cnt[i] + 1.0f);
}

__global__ void k_copy_int(const int* __restrict__ a, int* __restrict__ b, int n) {
    int i = blockIdx.x * blockDim.x + threadIdx.x;
    if (i < n) b[i] = a[i];
}

// csr_se packs (edge_type<<16)|src ; csr_eid keeps original edge id
__global__ void k_scatter(const int* __restrict__ ei, const int* __restrict__ et,
                          int* __restrict__ cursor, int* __restrict__ csr_se,
                          int* __restrict__ csr_eid) {
    int e = blockIdx.x * blockDim.x + threadIdx.x;
    if (e >= E) return;
    int d = ei[E + e];
    int pos = atomicAdd(&cursor[d], 1);
    csr_se[pos] = (et[e] << 16) | ei[e];
    csr_eid[pos] = e;
}

// ---------------- GCN ----------------
__global__ void k_h1(const float* __restrict__ x, const float* __restrict__ W,
                     float* __restrict__ h) {
    int idx = blockIdx.x * blockDim.x + threadIdx.x;
    if (idx >= N * 32) return;
    int n = idx >> 5, f = idx & 31;
    const float* xr = x + n * 4;
    float acc = 0.f;
#pragma unroll
    for (int c = 0; c < 4; ++c) acc += xr[c] * W[c * 32 + f];
    h[idx] = acc;
}

__global__ void k_agg32(const int* __restrict__ rowptr, const int* __restrict__ csr_se,
                        const float* __restrict__ dis, const float* __restrict__ h,
                        const float* __restrict__ b, float* __restrict__ c) {
    int idx = blockIdx.x * blockDim.x + threadIdx.x;
    if (idx >= N * 32) return;
    int d = idx >> 5, f = idx & 31;
    int beg = rowptr[d], end = rowptr[d + 1];
    float acc = 0.f;
    for (int i = beg; i < end; ++i) {
        int s = csr_se[i] & 0xFFFF;
        acc += dis[s] * h[s * 32 + f];
    }
    float dd = dis[d];
    c[idx] = dd * acc + dd * dd * h[idx] + b[f];
}

__global__ void k_h2(const float* __restrict__ c1, const float* __restrict__ W,
                     float* __restrict__ h) {
    int idx = blockIdx.x * blockDim.x + threadIdx.x;
    if (idx >= N * 128) return;
    int n = idx >> 7, f = idx & 127;
    const float* cr = c1 + n * 32;
    float acc = 0.f;
    for (int c = 0; c < 32; ++c) acc += lrelu(cr[c], 0.01f) * W[c * 128 + f];
    h[idx] = acc;
}

__global__ void k_kgcopy(const float* __restrict__ kg, float* __restrict__ x0) {
    int idx = blockIdx.x * blockDim.x + threadIdx.x;
    if (idx >= N * 128) return;
    int n = idx >> 7, f = idx & 127;
    x0[n * 256 + f] = kg[idx];
}

__global__ void k_agg128(const int* __restrict__ rowptr, const int* __restrict__ csr_se,
                         const float* __restrict__ dis, const float* __restrict__ h,
                         const float* __restrict__ b, float* __restrict__ x0) {
    int idx = blockIdx.x * blockDim.x + threadIdx.x;
    if (idx >= N * 128) return;
    int d = idx >> 7, f = idx & 127;
    int beg = rowptr[d], end = rowptr[d + 1];
    float acc = 0.f;
    for (int i = beg; i < end; ++i) {
        int s = csr_se[i] & 0xFFFF;
        acc += dis[s] * h[s * 128 + f];
    }
    float dd = dis[d];
    x0[d * 256 + 128 + f] = dd * acc + dd * dd * h[d * 128 + f] + b[f];
}

// ---------------- RGAT attention ----------------
__global__ void k_wqk(const float* __restrict__ W, const float* __restrict__ q,
                      const float* __restrict__ kmat, float* __restrict__ wq,
                      float* __restrict__ wk) {
    int idx = blockIdx.x * blockDim.x + threadIdx.x;
    if (idx >= R * 256 * H) return;
    int r = idx >> 10, i = (idx >> 2) & 255, h = idx & 3;
    const float* wr = W + ((long)r * 256 + i) * 256;
    float aq = 0.f, ak = 0.f;
    for (int o = 0; o < 256; ++o) {
        float wv = wr[o];
        aq += wv * q[o * 4 + h];
        ak += wv * kmat[o * 4 + h];
    }
    wq[i * 32 + r * 4 + h] = aq;
    wk[i * 32 + r * 4 + h] = ak;
}

__global__ void k_qnkn(const float* __restrict__ x, const float* __restrict__ wq,
                       const float* __restrict__ wk, float* __restrict__ qn,
                       float* __restrict__ kn) {
    int idx = blockIdx.x * blockDim.x + threadIdx.x;
    if (idx >= N * 32) return;
    int n = idx >> 5, rh = idx & 31;
    const float* xr = x + (long)n * 256;
    float aq = 0.f, ak = 0.f;
    for (int i = 0; i < 256; ++i) {
        float xv = xr[i];
        aq += xv * wq[i * 32 + rh];
        ak += xv * wk[i * 32 + rh];
    }
    qn[idx] = aq;
    kn[idx] = ak;
}

// fused per-(node,head) softmax over incoming edges; writes alpha in CSR order
// (for the gather) and in eid order (model output a1/a2)
__global__ void k_soft(const int* __restrict__ rowptr, const int* __restrict__ csr_se,
                       const int* __restrict__ csr_eid,
                       const float* __restrict__ qn, const float* __restrict__ kn,
                       float* __restrict__ alpha_csr, float* __restrict__ aout) {
    int idx = blockIdx.x * blockDim.x + threadIdx.x;
    if (idx >= N * H) return;
    int d = idx >> 2, h = idx & 3;
    int beg = rowptr[d], end = rowptr[d + 1];
    if (beg == end) return;
    float m = -1e30f;
    for (int i = beg; i < end; ++i) {
        int se = csr_se[i];
        int tt = se >> 16, s = se & 0xFFFF;
        float v = qn[d * 32 + tt * 4 + h] + kn[s * 32 + tt * 4 + h];
        v = lrelu(v, 0.2f);
        alpha_csr[i * 4 + h] = v;
        m = fmaxf(m, v);
    }
    float sum = 0.f;
    for (int i = beg; i < end; ++i) {
        float ex = expf(alpha_csr[i * 4 + h] - m);
        alpha_csr[i * 4 + h] = ex;
        sum += ex;
    }
    float inv = 1.f / sum;
    for (int i = beg; i < end; ++i) {
        float a = alpha_csr[i * 4 + h] * inv;
        alpha_csr[i * 4 + h] = a;
        aout[csr_eid[i] * 4 + h] = a;
    }
}

// ---------------- bf16 conversion / transpose ----------------
__global__ void k_xconv(const float* __restrict__ x, unsigned short* __restrict__ xb) {
    int idx = blockIdx.x * blockDim.x + threadIdx.x;
    if (idx < N * 256) xb[idx] = f2bf(x[idx]);
}

// Wt[z][n][k] = bf16(W[z][k][n])
__global__ void k_wconv(const float* __restrict__ W, unsigned short* __restrict__ Wt,
                        int zcnt) {
    int idx = blockIdx.x * blockDim.x + threadIdx.x;
    if (idx >= zcnt * 65536) return;
    int z = idx >> 16, k = (idx >> 8) & 255, n = idx & 255;
    Wt[((size_t)z << 16) + (n << 8) + k] = f2bf(W[idx]);
}

// ---------------- bf16 MFMA GEMM, relation-batched, register-prefetch pipeline --
// A: [M][256] bf16 row-major; Bt: [z][256(n)][256(k)] bf16.
// If Cf==nullptr: Cbf[z][M][256] = bf16(A@B[z]).  Else (NZ==1): Cf += A@B + bias.
// Block: 128x128 tile, 4 waves of 64x64; loops up to 4 z per block (A tile L1/L2-hot).
#define GBM 128
#define GBN 128
#define GBK 64
#define LP 72   // LDS pitch in bf16: 144B rows -> 16B aligned, 2-way banks (free)
__global__ __launch_bounds__(256) void gemm_mfma2(
    const unsigned short* __restrict__ A, const unsigned short* __restrict__ Bt,
    unsigned short* __restrict__ Cbf, float* __restrict__ Cf,
    const float* __restrict__ bias, int M, int NZ)
{
    __shared__ unsigned short As[GBM * LP];
    __shared__ unsigned short Bs[GBN * LP];
    int m0 = blockIdx.y * GBM;
    int n0 = blockIdx.x * GBN;
    int z0 = blockIdx.z * 4;
    int nzb = NZ - z0; if (nzb > 4) nzb = 4;
    int t = threadIdx.x;
    int wave = t >> 6, lane = t & 63;
    int wr = wave >> 1, wc = wave & 1;
    int lrow = lane & 15, kq = lane >> 4;
    int srow = t >> 3, skc = t & 7;

    f32x4 acc[4][4];
#pragma unroll
    for (int i = 0; i < 4; ++i)
#pragma unroll
        for (int j = 0; j < 4; ++j) acc[i][j] = (f32x4){0.f, 0.f, 0.f, 0.f};

    uint4 ra[4], rb[4];
    auto ld = [&](int zi, int k0) {
        const unsigned short* Bz = Bt + ((size_t)(z0 + zi) << 16);
        int kb = k0 * GBK;
#pragma unroll
        for (int i = 0; i < 4; ++i) {
            int row = srow + i * 32;
            int gm = m0 + row;
            uint4 va = {0, 0, 0, 0};
            if (gm < M) va = *(const uint4*)(A + (size_t)gm * 256 + kb + skc * 8);
            ra[i] = va;
            rb[i] = *(const uint4*)(Bz + (size_t)(n0 + row) * 256 + kb + skc * 8);
        }
    };

    ld(0, 0);
    int stages = nzb * 4;
    for (int s = 0; s < stages; ++s) {
        int zi = s >> 2;
        __syncthreads();
#pragma unroll
        for (int i = 0; i < 4; ++i) {
            int row = srow + i * 32;
            *(uint4*)(As + row * LP + skc * 8) = ra[i];
            *(uint4*)(Bs + row * LP + skc * 8) = rb[i];
        }
        if (s + 1 < stages) ld((s + 1) >> 2, (s + 1) & 3);
        __syncthreads();
#pragma unroll
        for (int kc = 0; kc < 2; ++kc) {
            short8 af[4], bf[4];
#pragma unroll
            for (int i = 0; i < 4; ++i)
                af[i] = *(const short8*)(As + (wr * 64 + i * 16 + lrow) * LP + kc * 32 + kq * 8);
#pragma unroll
            for (int j = 0; j < 4; ++j)
                bf[j] = *(const short8*)(Bs + (wc * 64 + j * 16 + lrow) * LP + kc * 32 + kq * 8);
#pragma unroll
            for (int i = 0; i < 4; ++i)
#pragma unroll
                for (int j = 0; j < 4; ++j)
                    acc[i][j] = __builtin_amdgcn_mfma_f32_16x16x32_bf16(af[i], bf[j],
                                                                       acc[i][j], 0, 0, 0);
        }
        if ((s & 3) == 3) {
            int z = z0 + zi;
            if (Cf) {
#pragma unroll
                for (int i = 0; i < 4; ++i)
#pragma unroll
                    for (int j = 0; j < 4; ++j) {
                        int gn = n0 + wc * 64 + j * 16 + lrow;
#pragma unroll
                        for (int reg = 0; reg < 4; ++reg) {
                            int gm = m0 + wr * 64 + i * 16 + kq * 4 + reg;
                            if (gm < M)
                                Cf[(size_t)gm * 256 + gn] += acc[i][j][reg] + bias[gn];
                        }
                    }
            } else {
#pragma unroll
                for (int i = 0; i < 4; ++i)
#pragma unroll
                    for (int j = 0; j < 4; ++j) {
                        int gn = n0 + wc * 64 + j * 16 + lrow;
#pragma unroll
                        for (int reg = 0; reg < 4; ++reg) {
                            int gm = m0 + wr * 64 + i * 16 + kq * 4 + reg;
                            if (gm < M)
                                Cbf[((size_t)z * M + gm) * 256 + gn] = f2bf(acc[i][j][reg]);
                        }
                    }
            }
#pragma unroll
            for (int i = 0; i < 4; ++i)
#pragma unroll
                for (int j = 0; j < 4; ++j) acc[i][j] = (f32x4){0.f, 0.f, 0.f, 0.f};
        }
    }
}

// ---------------- message aggregation (CSR gather) ----------------
__global__ void k_msg_gather(const int* __restrict__ rowptr, const int* __restrict__ csr_se,
                             const float* __restrict__ alpha_csr,
                             const unsigned short* __restrict__ xw,
                             const float* __restrict__ bias, float* __restrict__ out,
                             int r0, int r1, int first) {
    int gid = blockIdx.x * blockDim.x + threadIdx.x;
    int node = gid >> 6, lane = gid & 63;
    if (node >= N) return;
    float ax = 0.f, ay = 0.f, az = 0.f, aw = 0.f;
    int beg = rowptr[node], end = rowptr[node + 1];
    for (int i = beg; i < end; ++i) {
        int se = csr_se[i];
        int tt = se >> 16;
        if (tt < r0 || tt >= r1) continue;
        int s = se & 0xFFFF;
        float a = alpha_csr[i * 4 + (lane >> 4)];
        uint2 p = *(const uint2*)(xw + ((size_t)(tt - r0) * N + s) * 256 + lane * 4);
        ax += a * __uint_as_float(p.x << 16);
        ay += a * __uint_as_float(p.x & 0xFFFF0000u);
        az += a * __uint_as_float(p.y << 16);
        aw += a * __uint_as_float(p.y & 0xFFFF0000u);
    }
    float* o = out + (size_t)node * 256 + lane * 4;
    if (first) {
        const float4 b = ((const float4*)bias)[lane];
        o[0] = ax + b.x; o[1] = ay + b.y; o[2] = az + b.z; o[3] = aw + b.w;
    } else {
        o[0] += ax; o[1] += ay; o[2] += az; o[3] += aw;
    }
}

__global__ void k_leaky(float* p, int n) {
    int i = blockIdx.x * blockDim.x + threadIdx.x;
    if (i < n) p[i] = lrelu(p[i], 0.01f);
}

extern "C" void kernel_launch(void* const* d_in, const int* in_sizes, int n_in,
                              void* d_out, int out_size, void* d_ws, size_t ws_size,
                              hipStream_t stream) {
    const float* kg   = (const float*)d_in[0];
    const float* cc0  = (const float*)d_in[1];
    const float* gw1  = (const float*)d_in[2];
    const float* gb1  = (const float*)d_in[3];
    const float* gw2  = (const float*)d_in[4];
    const float* gb2  = (const float*)d_in[5];
    const float* r1w  = (const float*)d_in[6];
    const float* r1q  = (const float*)d_in[7];
    const float* r1k  = (const float*)d_in[8];
    const float* r1b  = (const float*)d_in[9];
    const float* r2w  = (const float*)d_in[10];
    const float* r2q  = (const float*)d_in[11];
    const float* r2k  = (const float*)d_in[12];
    const float* r2b  = (const float*)d_in[13];
    const float* linw = (const float*)d_in[14];
    const float* linb = (const float*)d_in[15];
    const int*   ei   = (const int*)d_in[16];
    const int*   et   = (const int*)d_in[17];

    float* out = (float*)d_out;
    float* a1  = out + (size_t)N * C;
    float* a2  = a1 + (size_t)E * H;

    float* ws = (float*)d_ws;
    size_t off = 0;
    float* dis  = ws + off; off += N;
    float* h1   = ws + off; off += (size_t)N * 32;
    float* c1   = ws + off; off += (size_t)N * 32;
    float* h2   = ws + off; off += (size_t)N * 128;
    float* x0   = ws + off; off += (size_t)N * C;
    float* hmid = ws + off; off += (size_t)N * C;
    float* qn   = ws + off; off += (size_t)N * R * H;
    float* kn   = ws + off; off += (size_t)N * R * H;
    float* wq   = ws + off; off += (size_t)R * 256 * H;
    float* wk   = ws + off; off += (size_t)R * 256 * H;
    int* cnt     = (int*)(ws + off); off += N;
    int* rowptr  = (int*)(ws + off); off += N + 1;
    int* cursor  = (int*)(ws + off); off += N;
    int* csr_se  = (int*)(ws + off); off += E;
    int* csr_eid = (int*)(ws + off); off += E;
    float* alpha = ws + off; off += (size_t)E * H;
    unsigned short* xb0 = (unsigned short*)(ws + off); off += (size_t)N * 128;
    unsigned short* xb1 = (unsigned short*)(ws + off); off += (size_t)N * 128;
    unsigned short* wt  = (unsigned short*)(ws + off); off += (size_t)R * 32768;
    unsigned short* wtl = (unsigned short*)(ws + off); off += 32768;
    unsigned short* xwb = (unsigned short*)(ws + off);

    size_t fixedB = off * 4;
    int K = R;  // relations materialized per chunk
    if (ws_size > fixedB) {
        size_t kmax = (ws_size - fixedB) / ((size_t)N * C * 2);
        if (kmax < (size_t)K) K = (int)kmax;
    } else {
        K = 1;
    }
    if (K < 1) K = 1;

    const int B = 256;
    auto cdiv = [](long a, long b) { return (int)((a + b - 1) / b); };

    // ---- CSR build ----
    k_zero_int<<<cdiv(N, B), B, 0, stream>>>(cnt, N);
    k_count<<<cdiv(E, B), B, 0, stream>>>(ei, cnt);
    k_scan<<<1, 1024, 0, stream>>>(cnt, rowptr);
    k_dis<<<cdiv(N, B), B, 0, stream>>>(cnt, dis);
    k_copy_int<<<cdiv(N, B), B, 0, stream>>>(rowptr, cursor, N);
    k_scatter<<<cdiv(E, B), B, 0, stream>>>(ei, et, cursor, csr_se, csr_eid);

    // ---- GCN ----
    k_h1<<<cdiv((long)N * 32, B), B, 0, stream>>>(cc0, gw1, h1);
    k_agg32<<<cdiv((long)N * 32, B), B, 0, stream>>>(rowptr, csr_se, dis, h1, gb1, c1);
    k_h2<<<cdiv((long)N * 128, B), B, 0, stream>>>(c1, gw2, h2);
    k_kgcopy<<<cdiv((long)N * 128, B), B, 0, stream>>>(kg, x0);
    k_agg128<<<cdiv((long)N * 128, B), B, 0, stream>>>(rowptr, csr_se, dis, h2, gb2, x0);

    auto rgat = [&](const float* xin, unsigned short* xb, const float* W,
                    const float* q, const float* kk, const float* b,
                    float* obuf, float* aout) {
        k_wqk<<<cdiv((long)R * 256 * H, B), B, 0, stream>>>(W, q, kk, wq, wk);
        k_qnkn<<<cdiv((long)N * R * H, B), B, 0, stream>>>(xin, wq, wk, qn, kn);
        k_soft<<<cdiv((long)N * H, B), B, 0, stream>>>(rowptr, csr_se, csr_eid,
                                                       qn, kn, alpha, aout);
        k_xconv<<<cdiv((long)N * 256, B), B, 0, stream>>>(xin, xb);
        k_wconv<<<cdiv((long)R * 65536, B), B, 0, stream>>>(W, wt, R);
        for (int r0 = 0; r0 < R; r0 += K) {
            int kc = (R - r0) < K ? (R - r0) : K;
            dim3 g(C / GBN, cdiv(N, GBM), cdiv(kc, 4));
            gemm_mfma2<<<g, 256, 0, stream>>>(xb, wt + ((size_t)r0 << 16), xwb,
                                              nullptr, nullptr, N, kc);
            k_msg_gather<<<cdiv((long)N * 64, B), B, 0, stream>>>(
                rowptr, csr_se, alpha, xwb, b, obuf, r0, r0 + kc, r0 == 0 ? 1 : 0);
        }
    };

    rgat(x0, xb0, r1w, r1q, r1k, r1b, hmid, a1);
    k_leaky<<<cdiv((long)N * C, B), B, 0, stream>>>(hmid, N * C);
    rgat(hmid, xb1, r2w, r2q, r2k, r2b, out, a2);

    // out += x0 @ lin_w + lin_b   (bf16 MFMA, fp32 accumulate)
    k_wconv<<<cdiv((long)65536, B), B, 0, stream>>>(linw, wtl, 1);
    dim3 g(C / GBN, cdiv(N, GBM), 1);
    gemm_mfma2<<<g, 256, 0, stream>>>(xb0, wtl, nullptr, out, linb, N, 1);
}

// Round 5
// 857.110 us; speedup vs baseline: 1.1209x; 1.1209x over previous
//
#include <hip/hip_runtime.h>
#include <cstdint>

static constexpr int N = 20000;
static constexpr int E = 320000;
static constexpr int R = 8;
static constexpr int H = 4;
static constexpr int C = 256;

using short8 = __attribute__((ext_vector_type(8))) short;
using f32x4  = __attribute__((ext_vector_type(4))) float;

__device__ __forceinline__ float lrelu(float x, float s) { return x >= 0.f ? x : s * x; }
__device__ __forceinline__ unsigned short f2bf(float f) {
    unsigned u = __float_as_uint(f);
    unsigned r = (u + 0x7FFFu + ((u >> 16) & 1u)) >> 16;
    return (unsigned short)r;
}

// ---------------- CSR build ----------------
__global__ void k_zero_int(int* p, int n) {
    int i = blockIdx.x * blockDim.x + threadIdx.x;
    if (i < n) p[i] = 0;
}

__global__ void k_count(const int* __restrict__ ei, int* __restrict__ cnt) {
    int e = blockIdx.x * blockDim.x + threadIdx.x;
    if (e < E) atomicAdd(&cnt[ei[E + e]], 1);
}

__global__ __launch_bounds__(1024) void k_scan(const int* __restrict__ cnt,
                                               int* __restrict__ rowptr) {
    __shared__ int part[1024];
    const int CH = (N + 1023) / 1024;  // 20
    int t = threadIdx.x;
    int base = t * CH;
    int sum = 0;
    for (int j = 0; j < CH; ++j) {
        int idx = base + j;
        if (idx < N) sum += cnt[idx];
    }
    part[t] = sum;
    __syncthreads();
    for (int off = 1; off < 1024; off <<= 1) {
        int v = 0;
        if (t >= off) v = part[t - off];
        __syncthreads();
        if (t >= off) part[t] += v;
        __syncthreads();
    }
    int run = part[t] - sum;
    for (int j = 0; j < CH; ++j) {
        int idx = base + j;
        if (idx < N) { rowptr[idx] = run; run += cnt[idx]; }
    }
    if (t == 1023) rowptr[N] = part[1023];
}

__global__ void k_dis(const int* __restrict__ cnt, float* __restrict__ dis) {
    int i = blockIdx.x * blockDim.x + threadIdx.x;
    if (i < N) dis[i] = rsqrtf((float)cnt[i] + 1.0f);
}

__global__ void k_copy_int(const int* __restrict__ a, int* __restrict__ b, int n) {
    int i = blockIdx.x * blockDim.x + threadIdx.x;
    if (i < n) b[i] = a[i];
}

// csr_se packs (edge_type<<16)|src ; csr_eid keeps original edge id
__global__ void k_scatter(const int* __restrict__ ei, const int* __restrict__ et,
                          int* __restrict__ cursor, int* __restrict__ csr_se,
                          int* __restrict__ csr_eid) {
    int e = blockIdx.x * blockDim.x + threadIdx.x;
    if (e >= E) return;
    int d = ei[E + e];
    int pos = atomicAdd(&cursor[d], 1);
    csr_se[pos] = (et[e] << 16) | ei[e];
    csr_eid[pos] = e;
}

// ---------------- GCN ----------------
__global__ void k_h1(const float* __restrict__ x, const float* __restrict__ W,
                     float* __restrict__ h) {
    int idx = blockIdx.x * blockDim.x + threadIdx.x;
    if (idx >= N * 32) return;
    int n = idx >> 5, f = idx & 31;
    const float* xr = x + n * 4;
    float acc = 0.f;
#pragma unroll
    for (int c = 0; c < 4; ++c) acc += xr[c] * W[c * 32 + f];
    h[idx] = acc;
}

__global__ void k_agg32(const int* __restrict__ rowptr, const int* __restrict__ csr_se,
                        const float* __restrict__ dis, const float* __restrict__ h,
                        const float* __restrict__ b, float* __restrict__ c) {
    int idx = blockIdx.x * blockDim.x + threadIdx.x;
    if (idx >= N * 32) return;
    int d = idx >> 5, f = idx & 31;
    int beg = rowptr[d], end = rowptr[d + 1];
    float acc = 0.f;
    for (int i = beg; i < end; ++i) {
        int s = csr_se[i] & 0xFFFF;
        acc += dis[s] * h[s * 32 + f];
    }
    float dd = dis[d];
    c[idx] = dd * acc + dd * dd * h[idx] + b[f];
}

__global__ void k_h2(const float* __restrict__ c1, const float* __restrict__ W,
                     float* __restrict__ h) {
    int idx = blockIdx.x * blockDim.x + threadIdx.x;
    if (idx >= N * 128) return;
    int n = idx >> 7, f = idx & 127;
    const float* cr = c1 + n * 32;
    float acc = 0.f;
    for (int c = 0; c < 32; ++c) acc += lrelu(cr[c], 0.01f) * W[c * 128 + f];
    h[idx] = acc;
}

__global__ void k_kgcopy(const float* __restrict__ kg, float* __restrict__ x0) {
    int idx = blockIdx.x * blockDim.x + threadIdx.x;
    if (idx >= N * 128) return;
    int n = idx >> 7, f = idx & 127;
    x0[n * 256 + f] = kg[idx];
}

__global__ void k_agg128(const int* __restrict__ rowptr, const int* __restrict__ csr_se,
                         const float* __restrict__ dis, const float* __restrict__ h,
                         const float* __restrict__ b, float* __restrict__ x0) {
    int idx = blockIdx.x * blockDim.x + threadIdx.x;
    if (idx >= N * 128) return;
    int d = idx >> 7, f = idx & 127;
    int beg = rowptr[d], end = rowptr[d + 1];
    float acc = 0.f;
    for (int i = beg; i < end; ++i) {
        int s = csr_se[i] & 0xFFFF;
        acc += dis[s] * h[s * 128 + f];
    }
    float dd = dis[d];
    x0[d * 256 + 128 + f] = dd * acc + dd * dd * h[d * 128 + f] + b[f];
}

// ---------------- RGAT attention ----------------
__global__ void k_wqk(const float* __restrict__ W, const float* __restrict__ q,
                      const float* __restrict__ kmat, float* __restrict__ wq,
                      float* __restrict__ wk) {
    int idx = blockIdx.x * blockDim.x + threadIdx.x;
    if (idx >= R * 256 * H) return;
    int r = idx >> 10, i = (idx >> 2) & 255, h = idx & 3;
    const float* wr = W + ((long)r * 256 + i) * 256;
    float aq = 0.f, ak = 0.f;
    for (int o = 0; o < 256; ++o) {
        float wv = wr[o];
        aq += wv * q[o * 4 + h];
        ak += wv * kmat[o * 4 + h];
    }
    wq[i * 32 + r * 4 + h] = aq;
    wk[i * 32 + r * 4 + h] = ak;
}

__global__ void k_qnkn(const float* __restrict__ x, const float* __restrict__ wq,
                       const float* __restrict__ wk, float* __restrict__ qn,
                       float* __restrict__ kn) {
    int idx = blockIdx.x * blockDim.x + threadIdx.x;
    if (idx >= N * 32) return;
    int n = idx >> 5, rh = idx & 31;
    const float* xr = x + (long)n * 256;
    float aq = 0.f, ak = 0.f;
    for (int i = 0; i < 256; ++i) {
        float xv = xr[i];
        aq += xv * wq[i * 32 + rh];
        ak += xv * wk[i * 32 + rh];
    }
    qn[idx] = aq;
    kn[idx] = ak;
}

// fused per-(node,head) softmax over incoming edges; writes alpha in CSR order
// (for the gather) and in eid order (model output a1/a2)
__global__ void k_soft(const int* __restrict__ rowptr, const int* __restrict__ csr_se,
                       const int* __restrict__ csr_eid,
                       const float* __restrict__ qn, const float* __restrict__ kn,
                       float* __restrict__ alpha_csr, float* __restrict__ aout) {
    int idx = blockIdx.x * blockDim.x + threadIdx.x;
    if (idx >= N * H) return;
    int d = idx >> 2, h = idx & 3;
    int beg = rowptr[d], end = rowptr[d + 1];
    if (beg == end) return;
    float m = -1e30f;
    for (int i = beg; i < end; ++i) {
        int se = csr_se[i];
        int tt = se >> 16, s = se & 0xFFFF;
        float v = qn[d * 32 + tt * 4 + h] + kn[s * 32 + tt * 4 + h];
        v = lrelu(v, 0.2f);
        alpha_csr[i * 4 + h] = v;
        m = fmaxf(m, v);
    }
    float sum = 0.f;
    for (int i = beg; i < end; ++i) {
        float ex = expf(alpha_csr[i * 4 + h] - m);
        alpha_csr[i * 4 + h] = ex;
        sum += ex;
    }
    float inv = 1.f / sum;
    for (int i = beg; i < end; ++i) {
        float a = alpha_csr[i * 4 + h] * inv;
        alpha_csr[i * 4 + h] = a;
        aout[csr_eid[i] * 4 + h] = a;
    }
}

// ---------------- bf16 conversion / transpose ----------------
__global__ void k_xconv(const float* __restrict__ x, unsigned short* __restrict__ xb) {
    int idx = blockIdx.x * blockDim.x + threadIdx.x;
    if (idx < N * 256) xb[idx] = f2bf(x[idx]);
}

// Wt[z][n][k] = bf16(W[z][k][n])
__global__ void k_wconv(const float* __restrict__ W, unsigned short* __restrict__ Wt,
                        int zcnt) {
    int idx = blockIdx.x * blockDim.x + threadIdx.x;
    if (idx >= zcnt * 65536) return;
    int z = idx >> 16, k = (idx >> 8) & 255, n = idx & 255;
    Wt[((size_t)z << 16) + (n << 8) + k] = f2bf(W[idx]);
}

// ---------------- bf16 MFMA GEMM, double-buffered LDS pipeline ----------------
// A: [M][256] bf16 row-major; Bt: [z][256(n)][256(k)] bf16.
// If Cf==nullptr: Cbf[z][M][256] = bf16(A@B[z]).  Else: Cf += A@B[z=0] + bias.
// Block: 128x128 tile, 4 waves of 64x64, one relation z per block (grid.z).
#define TM 128
#define TN 128
#define TK 32
#define LPP 40  // LDS pitch in bf16 (32+8): 16B-aligned rows, 2-way banks (free)
__global__ __launch_bounds__(256) void gemm_mfma3(
    const unsigned short* __restrict__ A, const unsigned short* __restrict__ Bt,
    unsigned short* __restrict__ Cbf, float* __restrict__ Cf,
    const float* __restrict__ bias, int M)
{
    __shared__ unsigned short As[2][TM * LPP];
    __shared__ unsigned short Bs[2][TN * LPP];
    int z = blockIdx.z;
    int m0 = blockIdx.y * TM;
    int n0 = blockIdx.x * TN;
    const unsigned short* Bz = Bt + ((size_t)z << 16);
    int t = threadIdx.x;
    int wave = t >> 6, lane = t & 63;
    int wr = wave >> 1, wc = wave & 1;
    int lrow = lane & 15, kq = lane >> 4;

    f32x4 acc[4][4];
#pragma unroll
    for (int i = 0; i < 4; ++i)
#pragma unroll
        for (int j = 0; j < 4; ++j) acc[i][j] = (f32x4){0.f, 0.f, 0.f, 0.f};

    uint4 ra[2], rb[2];
    auto ldg = [&](int k0) {
        int kb = k0 * TK;
#pragma unroll
        for (int i = 0; i < 2; ++i) {
            int c = t + i * 256;
            int row = c >> 2, kc = c & 3;
            int gm = m0 + row;
            uint4 va = {0, 0, 0, 0};
            if (gm < M) va = *(const uint4*)(A + (size_t)gm * 256 + kb + kc * 8);
            ra[i] = va;
            rb[i] = *(const uint4*)(Bz + (size_t)(n0 + row) * 256 + kb + kc * 8);
        }
    };
    auto sts = [&](int buf) {
#pragma unroll
        for (int i = 0; i < 2; ++i) {
            int c = t + i * 256;
            int row = c >> 2, kc = c & 3;
            *(uint4*)(&As[buf][row * LPP + kc * 8]) = ra[i];
            *(uint4*)(&Bs[buf][row * LPP + kc * 8]) = rb[i];
        }
    };

    ldg(0);
    sts(0);
    ldg(1);
    const int NK = 256 / TK;  // 8
    for (int k0 = 0; k0 < NK; ++k0) {
        __syncthreads();
        int cur = k0 & 1;
        if (k0 + 1 < NK) {
            sts(cur ^ 1);
            if (k0 + 2 < NK) ldg(k0 + 2);
        }
        short8 af[4], bf4[4];
#pragma unroll
        for (int i = 0; i < 4; ++i)
            af[i] = *(const short8*)(&As[cur][(wr * 64 + i * 16 + lrow) * LPP + kq * 8]);
#pragma unroll
        for (int j = 0; j < 4; ++j)
            bf4[j] = *(const short8*)(&Bs[cur][(wc * 64 + j * 16 + lrow) * LPP + kq * 8]);
#pragma unroll
        for (int i = 0; i < 4; ++i)
#pragma unroll
            for (int j = 0; j < 4; ++j)
                acc[i][j] = __builtin_amdgcn_mfma_f32_16x16x32_bf16(af[i], bf4[j],
                                                                   acc[i][j], 0, 0, 0);
    }
    // C/D layout: row = quad*4 + reg, col = lane&15
    if (Cf) {
#pragma unroll
        for (int i = 0; i < 4; ++i)
#pragma unroll
            for (int j = 0; j < 4; ++j) {
                int gn = n0 + wc * 64 + j * 16 + lrow;
#pragma unroll
                for (int reg = 0; reg < 4; ++reg) {
                    int gm = m0 + wr * 64 + i * 16 + kq * 4 + reg;
                    if (gm < M) Cf[(size_t)gm * 256 + gn] += acc[i][j][reg] + bias[gn];
                }
            }
    } else {
#pragma unroll
        for (int i = 0; i < 4; ++i)
#pragma unroll
            for (int j = 0; j < 4; ++j) {
                int gn = n0 + wc * 64 + j * 16 + lrow;
#pragma unroll
                for (int reg = 0; reg < 4; ++reg) {
                    int gm = m0 + wr * 64 + i * 16 + kq * 4 + reg;
                    if (gm < M)
                        Cbf[((size_t)z * M + gm) * 256 + gn] = f2bf(acc[i][j][reg]);
                }
            }
    }
}

// ---------------- message aggregation (CSR gather) ----------------
__global__ void k_msg_gather(const int* __restrict__ rowptr, const int* __restrict__ csr_se,
                             const float* __restrict__ alpha_csr,
                             const unsigned short* __restrict__ xw,
                             const float* __restrict__ bias, float* __restrict__ out,
                             int r0, int r1, int first) {
    int gid = blockIdx.x * blockDim.x + threadIdx.x;
    int node = gid >> 6, lane = gid & 63;
    if (node >= N) return;
    float ax = 0.f, ay = 0.f, az = 0.f, aw = 0.f;
    int beg = rowptr[node], end = rowptr[node + 1];
    for (int i = beg; i < end; ++i) {
        int se = csr_se[i];
        int tt = se >> 16;
        if (tt < r0 || tt >= r1) continue;
        int s = se & 0xFFFF;
        float a = alpha_csr[i * 4 + (lane >> 4)];
        uint2 p = *(const uint2*)(xw + ((size_t)(tt - r0) * N + s) * 256 + lane * 4);
        ax += a * __uint_as_float(p.x << 16);
        ay += a * __uint_as_float(p.x & 0xFFFF0000u);
        az += a * __uint_as_float(p.y << 16);
        aw += a * __uint_as_float(p.y & 0xFFFF0000u);
    }
    float* o = out + (size_t)node * 256 + lane * 4;
    if (first) {
        const float4 b = ((const float4*)bias)[lane];
        o[0] = ax + b.x; o[1] = ay + b.y; o[2] = az + b.z; o[3] = aw + b.w;
    } else {
        o[0] += ax; o[1] += ay; o[2] += az; o[3] += aw;
    }
}

__global__ void k_leaky(float* p, int n) {
    int i = blockIdx.x * blockDim.x + threadIdx.x;
    if (i < n) p[i] = lrelu(p[i], 0.01f);
}

extern "C" void kernel_launch(void* const* d_in, const int* in_sizes, int n_in,
                              void* d_out, int out_size, void* d_ws, size_t ws_size,
                              hipStream_t stream) {
    const float* kg   = (const float*)d_in[0];
    const float* cc0  = (const float*)d_in[1];
    const float* gw1  = (const float*)d_in[2];
    const float* gb1  = (const float*)d_in[3];
    const float* gw2  = (const float*)d_in[4];
    const float* gb2  = (const float*)d_in[5];
    const float* r1w  = (const float*)d_in[6];
    const float* r1q  = (const float*)d_in[7];
    const float* r1k  = (const float*)d_in[8];
    const float* r1b  = (const float*)d_in[9];
    const float* r2w  = (const float*)d_in[10];
    const float* r2q  = (const float*)d_in[11];
    const float* r2k  = (const float*)d_in[12];
    const float* r2b  = (const float*)d_in[13];
    const float* linw = (const float*)d_in[14];
    const float* linb = (const float*)d_in[15];
    const int*   ei   = (const int*)d_in[16];
    const int*   et   = (const int*)d_in[17];

    float* out = (float*)d_out;
    float* a1  = out + (size_t)N * C;
    float* a2  = a1 + (size_t)E * H;

    float* ws = (float*)d_ws;
    size_t off = 0;
    float* dis  = ws + off; off += N;
    float* h1   = ws + off; off += (size_t)N * 32;
    float* c1   = ws + off; off += (size_t)N * 32;
    float* h2   = ws + off; off += (size_t)N * 128;
    float* x0   = ws + off; off += (size_t)N * C;
    float* hmid = ws + off; off += (size_t)N * C;
    float* qn   = ws + off; off += (size_t)N * R * H;
    float* kn   = ws + off; off += (size_t)N * R * H;
    float* wq   = ws + off; off += (size_t)R * 256 * H;
    float* wk   = ws + off; off += (size_t)R * 256 * H;
    int* cnt     = (int*)(ws + off); off += N;
    int* rowptr  = (int*)(ws + off); off += N + 1;
    int* cursor  = (int*)(ws + off); off += N;
    int* csr_se  = (int*)(ws + off); off += E;
    int* csr_eid = (int*)(ws + off); off += E;
    float* alpha = ws + off; off += (size_t)E * H;
    unsigned short* xb0 = (unsigned short*)(ws + off); off += (size_t)N * 128;
    unsigned short* xb1 = (unsigned short*)(ws + off); off += (size_t)N * 128;
    unsigned short* wt  = (unsigned short*)(ws + off); off += (size_t)R * 32768;
    unsigned short* wtl = (unsigned short*)(ws + off); off += 32768;
    unsigned short* xwb = (unsigned short*)(ws + off);

    size_t fixedB = off * 4;
    int K = R;  // relations materialized per chunk
    if (ws_size > fixedB) {
        size_t kmax = (ws_size - fixedB) / ((size_t)N * C * 2);
        if (kmax < (size_t)K) K = (int)kmax;
    } else {
        K = 1;
    }
    if (K < 1) K = 1;

    const int B = 256;
    auto cdiv = [](long a, long b) { return (int)((a + b - 1) / b); };

    // ---- CSR build ----
    k_zero_int<<<cdiv(N, B), B, 0, stream>>>(cnt, N);
    k_count<<<cdiv(E, B), B, 0, stream>>>(ei, cnt);
    k_scan<<<1, 1024, 0, stream>>>(cnt, rowptr);
    k_dis<<<cdiv(N, B), B, 0, stream>>>(cnt, dis);
    k_copy_int<<<cdiv(N, B), B, 0, stream>>>(rowptr, cursor, N);
    k_scatter<<<cdiv(E, B), B, 0, stream>>>(ei, et, cursor, csr_se, csr_eid);

    // ---- GCN ----
    k_h1<<<cdiv((long)N * 32, B), B, 0, stream>>>(cc0, gw1, h1);
    k_agg32<<<cdiv((long)N * 32, B), B, 0, stream>>>(rowptr, csr_se, dis, h1, gb1, c1);
    k_h2<<<cdiv((long)N * 128, B), B, 0, stream>>>(c1, gw2, h2);
    k_kgcopy<<<cdiv((long)N * 128, B), B, 0, stream>>>(kg, x0);
    k_agg128<<<cdiv((long)N * 128, B), B, 0, stream>>>(rowptr, csr_se, dis, h2, gb2, x0);

    auto rgat = [&](const float* xin, unsigned short* xb, const float* W,
                    const float* q, const float* kk, const float* b,
                    float* obuf, float* aout) {
        k_wqk<<<cdiv((long)R * 256 * H, B), B, 0, stream>>>(W, q, kk, wq, wk);
        k_qnkn<<<cdiv((long)N * R * H, B), B, 0, stream>>>(xin, wq, wk, qn, kn);
        k_soft<<<cdiv((long)N * H, B), B, 0, stream>>>(rowptr, csr_se, csr_eid,
                                                       qn, kn, alpha, aout);
        k_xconv<<<cdiv((long)N * 256, B), B, 0, stream>>>(xin, xb);
        k_wconv<<<cdiv((long)R * 65536, B), B, 0, stream>>>(W, wt, R);
        for (int r0 = 0; r0 < R; r0 += K) {
            int kc = (R - r0) < K ? (R - r0) : K;
            dim3 g(C / TN, cdiv(N, TM), kc);
            gemm_mfma3<<<g, 256, 0, stream>>>(xb, wt + ((size_t)r0 << 16), xwb,
                                              nullptr, nullptr, N);
            k_msg_gather<<<cdiv((long)N * 64, B), B, 0, stream>>>(
                rowptr, csr_se, alpha, xwb, b, obuf, r0, r0 + kc, r0 == 0 ? 1 : 0);
        }
    };

    rgat(x0, xb0, r1w, r1q, r1k, r1b, hmid, a1);
    k_leaky<<<cdiv((long)N * C, B), B, 0, stream>>>(hmid, N * C);
    rgat(hmid, xb1, r2w, r2q, r2k, r2b, out, a2);

    // out += x0 @ lin_w + lin_b   (bf16 MFMA, fp32 accumulate)
    k_wconv<<<cdiv((long)65536, B), B, 0, stream>>>(linw, wtl, 1);
    dim3 g(C / TN, cdiv(N, TM), 1);
    gemm_mfma3<<<g, 256, 0, stream>>>(xb0, wtl, nullptr, out, linb, N);
}

// Round 6
// 658.557 us; speedup vs baseline: 1.4588x; 1.3015x over previous
//
#include <hip/hip_runtime.h>
#include <cstdint>

static constexpr int N = 20000;
static constexpr int E = 320000;
static constexpr int R = 8;
static constexpr int H = 4;
static constexpr int C = 256;

using short8 = __attribute__((ext_vector_type(8))) short;
using f32x4  = __attribute__((ext_vector_type(4))) float;

__device__ __forceinline__ float lrelu(float x, float s) { return x >= 0.f ? x : s * x; }
__device__ __forceinline__ unsigned short f2bf(float f) {
    unsigned u = __float_as_uint(f);
    unsigned r = (u + 0x7FFFu + ((u >> 16) & 1u)) >> 16;
    return (unsigned short)r;
}

// ---------------- CSR build ----------------
__global__ void k_zero_int(int* p, int n) {
    int i = blockIdx.x * blockDim.x + threadIdx.x;
    if (i < n) p[i] = 0;
}

__global__ void k_count(const int* __restrict__ ei, int* __restrict__ cnt) {
    int e = blockIdx.x * blockDim.x + threadIdx.x;
    if (e < E) atomicAdd(&cnt[ei[E + e]], 1);
}

__global__ __launch_bounds__(1024) void k_scan(const int* __restrict__ cnt,
                                               int* __restrict__ rowptr) {
    __shared__ int part[1024];
    const int CH = (N + 1023) / 1024;  // 20
    int t = threadIdx.x;
    int base = t * CH;
    int sum = 0;
    for (int j = 0; j < CH; ++j) {
        int idx = base + j;
        if (idx < N) sum += cnt[idx];
    }
    part[t] = sum;
    __syncthreads();
    for (int off = 1; off < 1024; off <<= 1) {
        int v = 0;
        if (t >= off) v = part[t - off];
        __syncthreads();
        if (t >= off) part[t] += v;
        __syncthreads();
    }
    int run = part[t] - sum;
    for (int j = 0; j < CH; ++j) {
        int idx = base + j;
        if (idx < N) { rowptr[idx] = run; run += cnt[idx]; }
    }
    if (t == 1023) rowptr[N] = part[1023];
}

__global__ void k_dis(const int* __restrict__ cnt, float* __restrict__ dis) {
    int i = blockIdx.x * blockDim.x + threadIdx.x;
    if (i < N) dis[i] = rsqrtf((float)cnt[i] + 1.0f);
}

__global__ void k_copy_int(const int* __restrict__ a, int* __restrict__ b, int n) {
    int i = blockIdx.x * blockDim.x + threadIdx.x;
    if (i < n) b[i] = a[i];
}

// csr_se packs (edge_type<<16)|src ; csr_eid keeps original edge id
__global__ void k_scatter(const int* __restrict__ ei, const int* __restrict__ et,
                          int* __restrict__ cursor, int* __restrict__ csr_se,
                          int* __restrict__ csr_eid) {
    int e = blockIdx.x * blockDim.x + threadIdx.x;
    if (e >= E) return;
    int d = ei[E + e];
    int pos = atomicAdd(&cursor[d], 1);
    csr_se[pos] = (et[e] << 16) | ei[e];
    csr_eid[pos] = e;
}

// ---------------- GCN ----------------
__global__ void k_h1(const float* __restrict__ x, const float* __restrict__ W,
                     float* __restrict__ h) {
    int idx = blockIdx.x * blockDim.x + threadIdx.x;
    if (idx >= N * 32) return;
    int n = idx >> 5, f = idx & 31;
    const float* xr = x + n * 4;
    float acc = 0.f;
#pragma unroll
    for (int c = 0; c < 4; ++c) acc += xr[c] * W[c * 32 + f];
    h[idx] = acc;
}

__global__ void k_agg32(const int* __restrict__ rowptr, const int* __restrict__ csr_se,
                        const float* __restrict__ dis, const float* __restrict__ h,
                        const float* __restrict__ b, float* __restrict__ c) {
    int idx = blockIdx.x * blockDim.x + threadIdx.x;
    if (idx >= N * 32) return;
    int d = idx >> 5, f = idx & 31;
    int beg = rowptr[d], end = rowptr[d + 1];
    float acc = 0.f;
    for (int i = beg; i < end; ++i) {
        int s = csr_se[i] & 0xFFFF;
        acc += dis[s] * h[s * 32 + f];
    }
    float dd = dis[d];
    c[idx] = dd * acc + dd * dd * h[idx] + b[f];
}

__global__ void k_h2(const float* __restrict__ c1, const float* __restrict__ W,
                     float* __restrict__ h) {
    int idx = blockIdx.x * blockDim.x + threadIdx.x;
    if (idx >= N * 128) return;
    int n = idx >> 7, f = idx & 127;
    const float* cr = c1 + n * 32;
    float acc = 0.f;
    for (int c = 0; c < 32; ++c) acc += lrelu(cr[c], 0.01f) * W[c * 128 + f];
    h[idx] = acc;
}

__global__ void k_kgcopy(const float* __restrict__ kg, float* __restrict__ x0) {
    int idx = blockIdx.x * blockDim.x + threadIdx.x;
    if (idx >= N * 128) return;
    int n = idx >> 7, f = idx & 127;
    x0[n * 256 + f] = kg[idx];
}

__global__ void k_agg128(const int* __restrict__ rowptr, const int* __restrict__ csr_se,
                         const float* __restrict__ dis, const float* __restrict__ h,
                         const float* __restrict__ b, float* __restrict__ x0) {
    int idx = blockIdx.x * blockDim.x + threadIdx.x;
    if (idx >= N * 128) return;
    int d = idx >> 7, f = idx & 127;
    int beg = rowptr[d], end = rowptr[d + 1];
    float acc = 0.f;
    int i = beg;
    for (; i + 2 <= end; i += 2) {
        int s0 = csr_se[i] & 0xFFFF;
        int s1 = csr_se[i + 1] & 0xFFFF;
        float d0 = dis[s0], d1 = dis[s1];
        float v0 = h[s0 * 128 + f], v1 = h[s1 * 128 + f];
        acc += d0 * v0 + d1 * v1;
    }
    if (i < end) {
        int s = csr_se[i] & 0xFFFF;
        acc += dis[s] * h[s * 128 + f];
    }
    float dd = dis[d];
    x0[d * 256 + 128 + f] = dd * acc + dd * dd * h[d * 128 + f] + b[f];
}

// ---------------- RGAT attention ----------------
__global__ void k_wqk(const float* __restrict__ W, const float* __restrict__ q,
                      const float* __restrict__ kmat, float* __restrict__ wq,
                      float* __restrict__ wk) {
    int idx = blockIdx.x * blockDim.x + threadIdx.x;
    if (idx >= R * 256 * H) return;
    int r = idx >> 10, i = (idx >> 2) & 255, h = idx & 3;
    const float* wr = W + ((long)r * 256 + i) * 256;
    float aq = 0.f, ak = 0.f;
    for (int o = 0; o < 256; ++o) {
        float wv = wr[o];
        aq += wv * q[o * 4 + h];
        ak += wv * kmat[o * 4 + h];
    }
    wq[i * 32 + r * 4 + h] = aq;
    wk[i * 32 + r * 4 + h] = ak;
}

// wqkb[n][k] bf16, n in [0,64): n<32 -> wq col n, else wk col n-32
__global__ void k_wqk_pack(const float* __restrict__ wq, const float* __restrict__ wk,
                           unsigned short* __restrict__ wqkb) {
    int idx = blockIdx.x * blockDim.x + threadIdx.x;
    if (idx >= 64 * 256) return;
    int n = idx >> 8, k = idx & 255;
    float v = (n < 32) ? wq[k * 32 + n] : wk[k * 32 + (n - 32)];
    wqkb[n * 256 + k] = f2bf(v);
}

// qn|kn = xb @ wqkb^T via MFMA.  Block: 256 thr = 4 waves, 64 rows per block.
#define QP 264  // LDS pitch (shorts) for wqkb rows
__global__ __launch_bounds__(256) void k_qnkn_mfma(
    const unsigned short* __restrict__ xb, const unsigned short* __restrict__ wqkb,
    float* __restrict__ qn, float* __restrict__ kn)
{
    __shared__ unsigned short Ws[64 * QP];
    int t = threadIdx.x;
    // stage wqkb: thread t -> row t>>2, 64-short chunk (t&3)
    {
        int r = t >> 2, off = (t & 3) * 64;
#pragma unroll
        for (int i = 0; i < 8; ++i)
            *(uint4*)(&Ws[r * QP + off + i * 8]) =
                *(const uint4*)(wqkb + r * 256 + off + i * 8);
    }
    __syncthreads();
    int wave = t >> 6, lane = t & 63;
    int lrow = lane & 15, kq = lane >> 4;
    int mw = blockIdx.x * 64 + wave * 16;  // 16 rows per wave
    int gm = mw + lrow;
    int gmc = gm < N ? gm : N - 1;

    f32x4 acc[4];
#pragma unroll
    for (int j = 0; j < 4; ++j) acc[j] = (f32x4){0.f, 0.f, 0.f, 0.f};

    for (int k0 = 0; k0 < 8; ++k0) {
        short8 af = *(const short8*)(xb + (size_t)gmc * 256 + k0 * 32 + kq * 8);
#pragma unroll
        for (int j = 0; j < 4; ++j) {
            short8 bf4 = *(const short8*)(&Ws[(j * 16 + lrow) * QP + k0 * 32 + kq * 8]);
            acc[j] = __builtin_amdgcn_mfma_f32_16x16x32_bf16(af, bf4, acc[j], 0, 0, 0);
        }
    }
#pragma unroll
    for (int j = 0; j < 4; ++j) {
        int col = j * 16 + lrow;
#pragma unroll
        for (int reg = 0; reg < 4; ++reg) {
            int gr = mw + kq * 4 + reg;
            if (gr < N) {
                if (col < 32) qn[gr * 32 + col] = acc[j][reg];
                else          kn[gr * 32 + (col - 32)] = acc[j][reg];
            }
        }
    }
}

// fused per-(node,head) softmax over incoming edges; writes alpha in CSR order
// (for the gather) and in eid order (model output a1/a2)
__global__ void k_soft(const int* __restrict__ rowptr, const int* __restrict__ csr_se,
                       const int* __restrict__ csr_eid,
                       const float* __restrict__ qn, const float* __restrict__ kn,
                       float* __restrict__ alpha_csr, float* __restrict__ aout) {
    int idx = blockIdx.x * blockDim.x + threadIdx.x;
    if (idx >= N * H) return;
    int d = idx >> 2, h = idx & 3;
    int beg = rowptr[d], end = rowptr[d + 1];
    if (beg == end) return;
    float m = -1e30f;
    for (int i = beg; i < end; ++i) {
        int se = csr_se[i];
        int tt = se >> 16, s = se & 0xFFFF;
        float v = qn[d * 32 + tt * 4 + h] + kn[s * 32 + tt * 4 + h];
        v = lrelu(v, 0.2f);
        alpha_csr[i * 4 + h] = v;
        m = fmaxf(m, v);
    }
    float sum = 0.f;
    for (int i = beg; i < end; ++i) {
        float ex = expf(alpha_csr[i * 4 + h] - m);
        alpha_csr[i * 4 + h] = ex;
        sum += ex;
    }
    float inv = 1.f / sum;
    for (int i = beg; i < end; ++i) {
        float a = alpha_csr[i * 4 + h] * inv;
        alpha_csr[i * 4 + h] = a;
        aout[csr_eid[i] * 4 + h] = a;
    }
}

// ---------------- bf16 conversion / transpose ----------------
__global__ void k_xconv(const float* __restrict__ x, unsigned short* __restrict__ xb) {
    int idx = blockIdx.x * blockDim.x + threadIdx.x;
    if (idx < N * 256) xb[idx] = f2bf(x[idx]);
}

// Wt[z][n][k] = bf16(W[z][k][n])
__global__ void k_wconv(const float* __restrict__ W, unsigned short* __restrict__ Wt,
                        int zcnt) {
    int idx = blockIdx.x * blockDim.x + threadIdx.x;
    if (idx >= zcnt * 65536) return;
    int z = idx >> 16, k = (idx >> 8) & 255, n = idx & 255;
    Wt[((size_t)z << 16) + (n << 8) + k] = f2bf(W[idx]);
}

// ---------------- bf16 MFMA GEMM (round-3 structure, z-innermost grid) ---------
// A: [M][256] bf16 row-major; Bt: [z][256(n)][256(k)] bf16.
// grid = (z, m-tiles, n-tiles): blocks with the same A-tile are adjacent -> L2 reuse.
// If Cf==nullptr: Cbf[z][M][256] = bf16(A@B[z]).  Else: Cf += A@B[z=0] + bias.
#define TM 128
#define TN 128
#define TK 32
#define LPP 40  // LDS pitch in bf16 (32+8): 16B-aligned rows, 2-way banks (free)
__global__ __launch_bounds__(256) void gemm_mfma3(
    const unsigned short* __restrict__ A, const unsigned short* __restrict__ Bt,
    unsigned short* __restrict__ Cbf, float* __restrict__ Cf,
    const float* __restrict__ bias, int M)
{
    __shared__ unsigned short As[TM * LPP];
    __shared__ unsigned short Bs[TN * LPP];
    int z = blockIdx.x;
    int m0 = blockIdx.y * TM;
    int n0 = blockIdx.z * TN;
    const unsigned short* Bz = Bt + ((size_t)z << 16);
    int t = threadIdx.x;
    int wave = t >> 6, lane = t & 63;
    int wr = wave >> 1, wc = wave & 1;
    int lrow = lane & 15, kq = lane >> 4;

    f32x4 acc[4][4];
#pragma unroll
    for (int i = 0; i < 4; ++i)
#pragma unroll
        for (int j = 0; j < 4; ++j) acc[i][j] = (f32x4){0.f, 0.f, 0.f, 0.f};

    for (int k0 = 0; k0 < 256; k0 += TK) {
#pragma unroll
        for (int i = 0; i < 2; ++i) {
            int c = t + i * 256;
            int row = c >> 2, kc = c & 3;
            int gm = m0 + row;
            uint4 va = {0, 0, 0, 0};
            if (gm < M) va = *(const uint4*)(A + (size_t)gm * 256 + k0 + kc * 8);
            *(uint4*)(&As[row * LPP + kc * 8]) = va;
            uint4 vb = *(const uint4*)(Bz + (size_t)(n0 + row) * 256 + k0 + kc * 8);
            *(uint4*)(&Bs[row * LPP + kc * 8]) = vb;
        }
        __syncthreads();
        short8 af[4], bf4[4];
#pragma unroll
        for (int i = 0; i < 4; ++i)
            af[i] = *(const short8*)(&As[(wr * 64 + i * 16 + lrow) * LPP + kq * 8]);
#pragma unroll
        for (int j = 0; j < 4; ++j)
            bf4[j] = *(const short8*)(&Bs[(wc * 64 + j * 16 + lrow) * LPP + kq * 8]);
#pragma unroll
        for (int i = 0; i < 4; ++i)
#pragma unroll
            for (int j = 0; j < 4; ++j)
                acc[i][j] = __builtin_amdgcn_mfma_f32_16x16x32_bf16(af[i], bf4[j],
                                                                   acc[i][j], 0, 0, 0);
        __syncthreads();
    }
    // C/D layout: row = quad*4 + reg, col = lane&15
    if (Cf) {
#pragma unroll
        for (int i = 0; i < 4; ++i)
#pragma unroll
            for (int j = 0; j < 4; ++j) {
                int gn = n0 + wc * 64 + j * 16 + lrow;
#pragma unroll
                for (int reg = 0; reg < 4; ++reg) {
                    int gm = m0 + wr * 64 + i * 16 + kq * 4 + reg;
                    if (gm < M) Cf[(size_t)gm * 256 + gn] += acc[i][j][reg] + bias[gn];
                }
            }
    } else {
#pragma unroll
        for (int i = 0; i < 4; ++i)
#pragma unroll
            for (int j = 0; j < 4; ++j) {
                int gn = n0 + wc * 64 + j * 16 + lrow;
#pragma unroll
                for (int reg = 0; reg < 4; ++reg) {
                    int gm = m0 + wr * 64 + i * 16 + kq * 4 + reg;
                    if (gm < M)
                        Cbf[((size_t)z * M + gm) * 256 + gn] = f2bf(acc[i][j][reg]);
                }
            }
    }
}

// ---------------- message aggregation (CSR gather, unroll-2) ----------------
__global__ void k_msg_gather(const int* __restrict__ rowptr, const int* __restrict__ csr_se,
                             const float* __restrict__ alpha_csr,
                             const unsigned short* __restrict__ xw,
                             const float* __restrict__ bias, float* __restrict__ out,
                             int r0, int r1, int first, int act) {
    int gid = blockIdx.x * blockDim.x + threadIdx.x;
    int node = gid >> 6, lane = gid & 63;
    if (node >= N) return;
    int hsel = lane >> 4;
    float ax = 0.f, ay = 0.f, az = 0.f, aw = 0.f;
    int beg = rowptr[node], end = rowptr[node + 1];
    int i = beg;
    for (; i + 2 <= end; i += 2) {
        int se0 = csr_se[i], se1 = csr_se[i + 1];
        int t0 = se0 >> 16, t1 = se1 >> 16;
        float a0 = alpha_csr[i * 4 + hsel];
        float a1v = alpha_csr[(i + 1) * 4 + hsel];
        if (t0 >= r0 && t0 < r1) {
            int s = se0 & 0xFFFF;
            uint2 p = *(const uint2*)(xw + ((size_t)(t0 - r0) * N + s) * 256 + lane * 4);
            ax += a0 * __uint_as_float(p.x << 16);
            ay += a0 * __uint_as_float(p.x & 0xFFFF0000u);
            az += a0 * __uint_as_float(p.y << 16);
            aw += a0 * __uint_as_float(p.y & 0xFFFF0000u);
        }
        if (t1 >= r0 && t1 < r1) {
            int s = se1 & 0xFFFF;
            uint2 p = *(const uint2*)(xw + ((size_t)(t1 - r0) * N + s) * 256 + lane * 4);
            ax += a1v * __uint_as_float(p.x << 16);
            ay += a1v * __uint_as_float(p.x & 0xFFFF0000u);
            az += a1v * __uint_as_float(p.y << 16);
            aw += a1v * __uint_as_float(p.y & 0xFFFF0000u);
        }
    }
    if (i < end) {
        int se = csr_se[i];
        int tt = se >> 16;
        if (tt >= r0 && tt < r1) {
            int s = se & 0xFFFF;
            float a = alpha_csr[i * 4 + hsel];
            uint2 p = *(const uint2*)(xw + ((size_t)(tt - r0) * N + s) * 256 + lane * 4);
            ax += a * __uint_as_float(p.x << 16);
            ay += a * __uint_as_float(p.x & 0xFFFF0000u);
            az += a * __uint_as_float(p.y << 16);
            aw += a * __uint_as_float(p.y & 0xFFFF0000u);
        }
    }
    float* o = out + (size_t)node * 256 + lane * 4;
    float vx, vy, vz, vw;
    if (first) {
        const float4 b = ((const float4*)bias)[lane];
        vx = ax + b.x; vy = ay + b.y; vz = az + b.z; vw = aw + b.w;
    } else {
        vx = o[0] + ax; vy = o[1] + ay; vz = o[2] + az; vw = o[3] + aw;
    }
    if (act) {
        vx = lrelu(vx, 0.01f); vy = lrelu(vy, 0.01f);
        vz = lrelu(vz, 0.01f); vw = lrelu(vw, 0.01f);
    }
    o[0] = vx; o[1] = vy; o[2] = vz; o[3] = vw;
}

extern "C" void kernel_launch(void* const* d_in, const int* in_sizes, int n_in,
                              void* d_out, int out_size, void* d_ws, size_t ws_size,
                              hipStream_t stream) {
    const float* kg   = (const float*)d_in[0];
    const float* cc0  = (const float*)d_in[1];
    const float* gw1  = (const float*)d_in[2];
    const float* gb1  = (const float*)d_in[3];
    const float* gw2  = (const float*)d_in[4];
    const float* gb2  = (const float*)d_in[5];
    const float* r1w  = (const float*)d_in[6];
    const float* r1q  = (const float*)d_in[7];
    const float* r1k  = (const float*)d_in[8];
    const float* r1b  = (const float*)d_in[9];
    const float* r2w  = (const float*)d_in[10];
    const float* r2q  = (const float*)d_in[11];
    const float* r2k  = (const float*)d_in[12];
    const float* r2b  = (const float*)d_in[13];
    const float* linw = (const float*)d_in[14];
    const float* linb = (const float*)d_in[15];
    const int*   ei   = (const int*)d_in[16];
    const int*   et   = (const int*)d_in[17];

    float* out = (float*)d_out;
    float* a1  = out + (size_t)N * C;
    float* a2  = a1 + (size_t)E * H;

    float* ws = (float*)d_ws;
    size_t off = 0;
    float* dis  = ws + off; off += N;
    float* h1   = ws + off; off += (size_t)N * 32;
    float* c1   = ws + off; off += (size_t)N * 32;
    float* h2   = ws + off; off += (size_t)N * 128;
    float* x0   = ws + off; off += (size_t)N * C;
    float* hmid = ws + off; off += (size_t)N * C;
    float* qn   = ws + off; off += (size_t)N * R * H;
    float* kn   = ws + off; off += (size_t)N * R * H;
    float* wq   = ws + off; off += (size_t)R * 256 * H;
    float* wk   = ws + off; off += (size_t)R * 256 * H;
    int* cnt     = (int*)(ws + off); off += N;
    int* rowptr  = (int*)(ws + off); off += N + 1;
    int* cursor  = (int*)(ws + off); off += N;
    int* csr_se  = (int*)(ws + off); off += E;
    int* csr_eid = (int*)(ws + off); off += E;
    float* alpha = ws + off; off += (size_t)E * H;
    unsigned short* xb0 = (unsigned short*)(ws + off); off += (size_t)N * 128;
    unsigned short* xb1 = (unsigned short*)(ws + off); off += (size_t)N * 128;
    unsigned short* wt  = (unsigned short*)(ws + off); off += (size_t)R * 32768;
    unsigned short* wtl = (unsigned short*)(ws + off); off += 32768;
    unsigned short* wqkb = (unsigned short*)(ws + off); off += 8192;  // 64*256 bf16
    unsigned short* xwb = (unsigned short*)(ws + off);

    size_t fixedB = off * 4;
    int K = R;  // relations materialized per chunk
    if (ws_size > fixedB) {
        size_t kmax = (ws_size - fixedB) / ((size_t)N * C * 2);
        if (kmax < (size_t)K) K = (int)kmax;
    } else {
        K = 1;
    }
    if (K < 1) K = 1;

    const int B = 256;
    auto cdiv = [](long a, long b) { return (int)((a + b - 1) / b); };

    // ---- CSR build ----
    k_zero_int<<<cdiv(N, B), B, 0, stream>>>(cnt, N);
    k_count<<<cdiv(E, B), B, 0, stream>>>(ei, cnt);
    k_scan<<<1, 1024, 0, stream>>>(cnt, rowptr);
    k_dis<<<cdiv(N, B), B, 0, stream>>>(cnt, dis);
    k_copy_int<<<cdiv(N, B), B, 0, stream>>>(rowptr, cursor, N);
    k_scatter<<<cdiv(E, B), B, 0, stream>>>(ei, et, cursor, csr_se, csr_eid);

    // ---- GCN ----
    k_h1<<<cdiv((long)N * 32, B), B, 0, stream>>>(cc0, gw1, h1);
    k_agg32<<<cdiv((long)N * 32, B), B, 0, stream>>>(rowptr, csr_se, dis, h1, gb1, c1);
    k_h2<<<cdiv((long)N * 128, B), B, 0, stream>>>(c1, gw2, h2);
    k_kgcopy<<<cdiv((long)N * 128, B), B, 0, stream>>>(kg, x0);
    k_agg128<<<cdiv((long)N * 128, B), B, 0, stream>>>(rowptr, csr_se, dis, h2, gb2, x0);

    auto rgat = [&](const float* xin, unsigned short* xb, const float* W,
                    const float* q, const float* kk, const float* b,
                    float* obuf, float* aout, int act) {
        k_xconv<<<cdiv((long)N * 256, B), B, 0, stream>>>(xin, xb);
        k_wqk<<<cdiv((long)R * 256 * H, B), B, 0, stream>>>(W, q, kk, wq, wk);
        k_wqk_pack<<<cdiv((long)64 * 256, B), B, 0, stream>>>(wq, wk, wqkb);
        k_qnkn_mfma<<<cdiv(N, 64), B, 0, stream>>>(xb, wqkb, qn, kn);
        k_soft<<<cdiv((long)N * H, B), B, 0, stream>>>(rowptr, csr_se, csr_eid,
                                                       qn, kn, alpha, aout);
        k_wconv<<<cdiv((long)R * 65536, B), B, 0, stream>>>(W, wt, R);
        for (int r0 = 0; r0 < R; r0 += K) {
            int kc = (R - r0) < K ? (R - r0) : K;
            dim3 g(kc, cdiv(N, TM), C / TN);
            gemm_mfma3<<<g, 256, 0, stream>>>(xb, wt + ((size_t)r0 << 16), xwb,
                                              nullptr, nullptr, N);
            int last = (r0 + kc >= R) ? 1 : 0;
            k_msg_gather<<<cdiv((long)N * 64, B), B, 0, stream>>>(
                rowptr, csr_se, alpha, xwb, b, obuf, r0, r0 + kc,
                r0 == 0 ? 1 : 0, act && last);
        }
    };

    rgat(x0, xb0, r1w, r1q, r1k, r1b, hmid, a1, 1);
    rgat(hmid, xb1, r2w, r2q, r2k, r2b, out, a2, 0);

    // out += x0 @ lin_w + lin_b   (bf16 MFMA, fp32 accumulate)
    k_wconv<<<cdiv((long)65536, B), B, 0, stream>>>(linw, wtl, 1);
    dim3 g(1, cdiv(N, TM), C / TN);
    gemm_mfma3<<<g, 256, 0, stream>>>(xb0, wtl, nullptr, out, linb, N);
}

// Round 7
// 621.903 us; speedup vs baseline: 1.5448x; 1.0589x over previous
//
#include <hip/hip_runtime.h>
#include <cstdint>

static constexpr int N = 20000;
static constexpr int E = 320000;
static constexpr int R = 8;
static constexpr int H = 4;
static constexpr int C = 256;

using short8 = __attribute__((ext_vector_type(8))) short;
using f32x4  = __attribute__((ext_vector_type(4))) float;

__device__ __forceinline__ float lrelu(float x, float s) { return x >= 0.f ? x : s * x; }
__device__ __forceinline__ unsigned short f2bf(float f) {
    unsigned u = __float_as_uint(f);
    unsigned r = (u + 0x7FFFu + ((u >> 16) & 1u)) >> 16;
    return (unsigned short)r;
}
__device__ __forceinline__ float bf2f(unsigned short s) {
    return __uint_as_float(((unsigned)s) << 16);
}

// ---------------- CSR build ----------------
__global__ void k_zero_int(int* p, int n) {
    int i = blockIdx.x * blockDim.x + threadIdx.x;
    if (i < n) p[i] = 0;
}

__global__ void k_count(const int* __restrict__ ei, int* __restrict__ cnt) {
    int e = blockIdx.x * blockDim.x + threadIdx.x;
    if (e < E) atomicAdd(&cnt[ei[E + e]], 1);
}

__global__ __launch_bounds__(1024) void k_scan(const int* __restrict__ cnt,
                                               int* __restrict__ rowptr) {
    __shared__ int part[1024];
    const int CH = (N + 1023) / 1024;  // 20
    int t = threadIdx.x;
    int base = t * CH;
    int sum = 0;
    for (int j = 0; j < CH; ++j) {
        int idx = base + j;
        if (idx < N) sum += cnt[idx];
    }
    part[t] = sum;
    __syncthreads();
    for (int off = 1; off < 1024; off <<= 1) {
        int v = 0;
        if (t >= off) v = part[t - off];
        __syncthreads();
        if (t >= off) part[t] += v;
        __syncthreads();
    }
    int run = part[t] - sum;
    for (int j = 0; j < CH; ++j) {
        int idx = base + j;
        if (idx < N) { rowptr[idx] = run; run += cnt[idx]; }
    }
    if (t == 1023) rowptr[N] = part[1023];
}

__global__ void k_dis(const int* __restrict__ cnt, float* __restrict__ dis) {
    int i = blockIdx.x * blockDim.x + threadIdx.x;
    if (i < N) dis[i] = rsqrtf((float)cnt[i] + 1.0f);
}

__global__ void k_copy_int(const int* __restrict__ a, int* __restrict__ b, int n) {
    int i = blockIdx.x * blockDim.x + threadIdx.x;
    if (i < n) b[i] = a[i];
}

// csr_se packs (edge_type<<16)|src ; csr_eid keeps original edge id
__global__ void k_scatter(const int* __restrict__ ei, const int* __restrict__ et,
                          int* __restrict__ cursor, int* __restrict__ csr_se,
                          int* __restrict__ csr_eid) {
    int e = blockIdx.x * blockDim.x + threadIdx.x;
    if (e >= E) return;
    int d = ei[E + e];
    int pos = atomicAdd(&cursor[d], 1);
    csr_se[pos] = (et[e] << 16) | ei[e];
    csr_eid[pos] = e;
}

// ---------------- GCN ----------------
__global__ void k_h1(const float* __restrict__ x, const float* __restrict__ W,
                     float* __restrict__ h) {
    int idx = blockIdx.x * blockDim.x + threadIdx.x;
    if (idx >= N * 32) return;
    int n = idx >> 5, f = idx & 31;
    const float* xr = x + n * 4;
    float acc = 0.f;
#pragma unroll
    for (int c = 0; c < 4; ++c) acc += xr[c] * W[c * 32 + f];
    h[idx] = acc;
}

__global__ void k_agg32(const int* __restrict__ rowptr, const int* __restrict__ csr_se,
                        const float* __restrict__ dis, const float* __restrict__ h,
                        const float* __restrict__ b, float* __restrict__ c) {
    int idx = blockIdx.x * blockDim.x + threadIdx.x;
    if (idx >= N * 32) return;
    int d = idx >> 5, f = idx & 31;
    int beg = rowptr[d], end = rowptr[d + 1];
    float acc = 0.f;
    for (int i = beg; i < end; ++i) {
        int s = csr_se[i] & 0xFFFF;
        acc += dis[s] * h[s * 32 + f];
    }
    float dd = dis[d];
    c[idx] = dd * acc + dd * dd * h[idx] + b[f];
}

// h2 stored bf16 (halves the random gather traffic in k_agg128)
__global__ void k_h2(const float* __restrict__ c1, const float* __restrict__ W,
                     unsigned short* __restrict__ h) {
    int idx = blockIdx.x * blockDim.x + threadIdx.x;
    if (idx >= N * 128) return;
    int n = idx >> 7, f = idx & 127;
    const float* cr = c1 + n * 32;
    float acc = 0.f;
    for (int c = 0; c < 32; ++c) acc += lrelu(cr[c], 0.01f) * W[c * 128 + f];
    h[idx] = f2bf(acc);
}

// writes x0 (fp32) and xb0 (bf16) kg half
__global__ void k_kgcopy(const float* __restrict__ kg, float* __restrict__ x0,
                         unsigned short* __restrict__ xb0) {
    int idx = blockIdx.x * blockDim.x + threadIdx.x;
    if (idx >= N * 128) return;
    int n = idx >> 7, f = idx & 127;
    float v = kg[idx];
    x0[n * 256 + f] = v;
    xb0[n * 256 + f] = f2bf(v);
}

__global__ void k_agg128(const int* __restrict__ rowptr, const int* __restrict__ csr_se,
                         const float* __restrict__ dis,
                         const unsigned short* __restrict__ h,
                         const float* __restrict__ b, float* __restrict__ x0,
                         unsigned short* __restrict__ xb0) {
    int idx = blockIdx.x * blockDim.x + threadIdx.x;
    if (idx >= N * 128) return;
    int d = idx >> 7, f = idx & 127;
    int beg = rowptr[d], end = rowptr[d + 1];
    float acc = 0.f;
    int i = beg;
    for (; i + 2 <= end; i += 2) {
        int s0 = csr_se[i] & 0xFFFF;
        int s1 = csr_se[i + 1] & 0xFFFF;
        float d0 = dis[s0], d1 = dis[s1];
        float v0 = bf2f(h[s0 * 128 + f]), v1 = bf2f(h[s1 * 128 + f]);
        acc += d0 * v0 + d1 * v1;
    }
    if (i < end) {
        int s = csr_se[i] & 0xFFFF;
        acc += dis[s] * bf2f(h[s * 128 + f]);
    }
    float dd = dis[d];
    float v = dd * acc + dd * dd * bf2f(h[d * 128 + f]) + b[f];
    x0[d * 256 + 128 + f] = v;
    xb0[d * 256 + 128 + f] = f2bf(v);
}

// ---------------- RGAT attention ----------------
__global__ void k_wqk(const float* __restrict__ W, const float* __restrict__ q,
                      const float* __restrict__ kmat, float* __restrict__ wq,
                      float* __restrict__ wk) {
    int idx = blockIdx.x * blockDim.x + threadIdx.x;
    if (idx >= R * 256 * H) return;
    int r = idx >> 10, i = (idx >> 2) & 255, h = idx & 3;
    const float* wr = W + ((long)r * 256 + i) * 256;
    float aq = 0.f, ak = 0.f;
    for (int o = 0; o < 256; ++o) {
        float wv = wr[o];
        aq += wv * q[o * 4 + h];
        ak += wv * kmat[o * 4 + h];
    }
    wq[i * 32 + r * 4 + h] = aq;
    wk[i * 32 + r * 4 + h] = ak;
}

// wqkb[n][k] bf16, n in [0,64): n<32 -> wq col n, else wk col n-32
__global__ void k_wqk_pack(const float* __restrict__ wq, const float* __restrict__ wk,
                           unsigned short* __restrict__ wqkb) {
    int idx = blockIdx.x * blockDim.x + threadIdx.x;
    if (idx >= 64 * 256) return;
    int n = idx >> 8, k = idx & 255;
    float v = (n < 32) ? wq[k * 32 + n] : wk[k * 32 + (n - 32)];
    wqkb[n * 256 + k] = f2bf(v);
}

// qn|kn = xb @ wqkb^T via MFMA.  Block: 256 thr = 4 waves, 64 rows per block.
#define QP 264
__global__ __launch_bounds__(256) void k_qnkn_mfma(
    const unsigned short* __restrict__ xb, const unsigned short* __restrict__ wqkb,
    float* __restrict__ qn, float* __restrict__ kn)
{
    __shared__ unsigned short Ws[64 * QP];
    int t = threadIdx.x;
    {
        int r = t >> 2, off = (t & 3) * 64;
#pragma unroll
        for (int i = 0; i < 8; ++i)
            *(uint4*)(&Ws[r * QP + off + i * 8]) =
                *(const uint4*)(wqkb + r * 256 + off + i * 8);
    }
    __syncthreads();
    int wave = t >> 6, lane = t & 63;
    int lrow = lane & 15, kq = lane >> 4;
    int mw = blockIdx.x * 64 + wave * 16;
    int gm = mw + lrow;
    int gmc = gm < N ? gm : N - 1;

    f32x4 acc[4];
#pragma unroll
    for (int j = 0; j < 4; ++j) acc[j] = (f32x4){0.f, 0.f, 0.f, 0.f};

    for (int k0 = 0; k0 < 8; ++k0) {
        short8 af = *(const short8*)(xb + (size_t)gmc * 256 + k0 * 32 + kq * 8);
#pragma unroll
        for (int j = 0; j < 4; ++j) {
            short8 bf4 = *(const short8*)(&Ws[(j * 16 + lrow) * QP + k0 * 32 + kq * 8]);
            acc[j] = __builtin_amdgcn_mfma_f32_16x16x32_bf16(af, bf4, acc[j], 0, 0, 0);
        }
    }
#pragma unroll
    for (int j = 0; j < 4; ++j) {
        int col = j * 16 + lrow;
#pragma unroll
        for (int reg = 0; reg < 4; ++reg) {
            int gr = mw + kq * 4 + reg;
            if (gr < N) {
                if (col < 32) qn[gr * 32 + col] = acc[j][reg];
                else          kn[gr * 32 + (col - 32)] = acc[j][reg];
            }
        }
    }
}

// fused per-(node,head) softmax over incoming edges
__global__ void k_soft(const int* __restrict__ rowptr, const int* __restrict__ csr_se,
                       const int* __restrict__ csr_eid,
                       const float* __restrict__ qn, const float* __restrict__ kn,
                       float* __restrict__ alpha_csr, float* __restrict__ aout) {
    int idx = blockIdx.x * blockDim.x + threadIdx.x;
    if (idx >= N * H) return;
    int d = idx >> 2, h = idx & 3;
    int beg = rowptr[d], end = rowptr[d + 1];
    if (beg == end) return;
    float m = -1e30f;
    for (int i = beg; i < end; ++i) {
        int se = csr_se[i];
        int tt = se >> 16, s = se & 0xFFFF;
        float v = qn[d * 32 + tt * 4 + h] + kn[s * 32 + tt * 4 + h];
        v = lrelu(v, 0.2f);
        alpha_csr[i * 4 + h] = v;
        m = fmaxf(m, v);
    }
    float sum = 0.f;
    for (int i = beg; i < end; ++i) {
        float ex = expf(alpha_csr[i * 4 + h] - m);
        alpha_csr[i * 4 + h] = ex;
        sum += ex;
    }
    float inv = 1.f / sum;
    for (int i = beg; i < end; ++i) {
        float a = alpha_csr[i * 4 + h] * inv;
        alpha_csr[i * 4 + h] = a;
        aout[csr_eid[i] * 4 + h] = a;
    }
}

// Wt[z][n][k] = bf16(W[z][k][n])
__global__ void k_wconv(const float* __restrict__ W, unsigned short* __restrict__ Wt,
                        int zcnt) {
    int idx = blockIdx.x * blockDim.x + threadIdx.x;
    if (idx >= zcnt * 65536) return;
    int z = idx >> 16, k = (idx >> 8) & 255, n = idx & 255;
    Wt[((size_t)z << 16) + (n << 8) + k] = f2bf(W[idx]);
}

// ---------------- bf16 MFMA GEMM, XCD-aware swizzled 1D grid ----------------
// All NZ*NT blocks sharing one A m-tile get the same (blockIdx%8) -> same XCD,
// so the A tile is fetched once per XCD and re-served from that XCD's L2.
// If Cf==nullptr: Cbf[z][M][256] = bf16(A@B[z]).  Else: Cf += A@B[z=0] + bias.
#define TM 128
#define TN 128
#define TK 32
#define LPP 40
__global__ __launch_bounds__(256) void gemm_mfma3(
    const unsigned short* __restrict__ A, const unsigned short* __restrict__ Bt,
    unsigned short* __restrict__ Cbf, float* __restrict__ Cf,
    const float* __restrict__ bias, int M, int NZ, int NT, int MT)
{
    int bi = blockIdx.x;
    int c = bi & 7;
    int g = bi >> 3;
    int per = NZ * NT;
    int mh = g / per;
    int j  = g % per;
    int mt = mh * 8 + c;
    if (mt >= MT) return;
    int z  = j % NZ;
    int nb = j / NZ;
    int m0 = mt * TM;
    int n0 = nb * TN;

    __shared__ unsigned short As[TM * LPP];
    __shared__ unsigned short Bs[TN * LPP];
    const unsigned short* Bz = Bt + ((size_t)z << 16);
    int t = threadIdx.x;
    int wave = t >> 6, lane = t & 63;
    int wr = wave >> 1, wc = wave & 1;
    int lrow = lane & 15, kq = lane >> 4;

    f32x4 acc[4][4];
#pragma unroll
    for (int i = 0; i < 4; ++i)
#pragma unroll
        for (int jj = 0; jj < 4; ++jj) acc[i][jj] = (f32x4){0.f, 0.f, 0.f, 0.f};

    for (int k0 = 0; k0 < 256; k0 += TK) {
#pragma unroll
        for (int i = 0; i < 2; ++i) {
            int cc = t + i * 256;
            int row = cc >> 2, kc = cc & 3;
            int gm = m0 + row;
            uint4 va = {0, 0, 0, 0};
            if (gm < M) va = *(const uint4*)(A + (size_t)gm * 256 + k0 + kc * 8);
            *(uint4*)(&As[row * LPP + kc * 8]) = va;
            uint4 vb = *(const uint4*)(Bz + (size_t)(n0 + row) * 256 + k0 + kc * 8);
            *(uint4*)(&Bs[row * LPP + kc * 8]) = vb;
        }
        __syncthreads();
        short8 af[4], bf4[4];
#pragma unroll
        for (int i = 0; i < 4; ++i)
            af[i] = *(const short8*)(&As[(wr * 64 + i * 16 + lrow) * LPP + kq * 8]);
#pragma unroll
        for (int jj = 0; jj < 4; ++jj)
            bf4[jj] = *(const short8*)(&Bs[(wc * 64 + jj * 16 + lrow) * LPP + kq * 8]);
#pragma unroll
        for (int i = 0; i < 4; ++i)
#pragma unroll
            for (int jj = 0; jj < 4; ++jj)
                acc[i][jj] = __builtin_amdgcn_mfma_f32_16x16x32_bf16(af[i], bf4[jj],
                                                                     acc[i][jj], 0, 0, 0);
        __syncthreads();
    }
    if (Cf) {
#pragma unroll
        for (int i = 0; i < 4; ++i)
#pragma unroll
            for (int jj = 0; jj < 4; ++jj) {
                int gn = n0 + wc * 64 + jj * 16 + lrow;
#pragma unroll
                for (int reg = 0; reg < 4; ++reg) {
                    int gm = m0 + wr * 64 + i * 16 + kq * 4 + reg;
                    if (gm < M) Cf[(size_t)gm * 256 + gn] += acc[i][jj][reg] + bias[gn];
                }
            }
    } else {
#pragma unroll
        for (int i = 0; i < 4; ++i)
#pragma unroll
            for (int jj = 0; jj < 4; ++jj) {
                int gn = n0 + wc * 64 + jj * 16 + lrow;
#pragma unroll
                for (int reg = 0; reg < 4; ++reg) {
                    int gm = m0 + wr * 64 + i * 16 + kq * 4 + reg;
                    if (gm < M)
                        Cbf[((size_t)z * M + gm) * 256 + gn] = f2bf(acc[i][jj][reg]);
                }
            }
    }
}

// ---------------- message aggregation (CSR gather, unroll-2) ----------------
// act!=0 (layer-1 last chunk): applies leaky and also writes bf16 copy to xbout
__global__ void k_msg_gather(const int* __restrict__ rowptr, const int* __restrict__ csr_se,
                             const float* __restrict__ alpha_csr,
                             const unsigned short* __restrict__ xw,
                             const float* __restrict__ bias, float* __restrict__ out,
                             unsigned short* __restrict__ xbout,
                             int r0, int r1, int first, int act) {
    int gid = blockIdx.x * blockDim.x + threadIdx.x;
    int node = gid >> 6, lane = gid & 63;
    if (node >= N) return;
    int hsel = lane >> 4;
    float ax = 0.f, ay = 0.f, az = 0.f, aw = 0.f;
    int beg = rowptr[node], end = rowptr[node + 1];
    int i = beg;
    for (; i + 2 <= end; i += 2) {
        int se0 = csr_se[i], se1 = csr_se[i + 1];
        int t0 = se0 >> 16, t1 = se1 >> 16;
        float a0 = alpha_csr[i * 4 + hsel];
        float a1v = alpha_csr[(i + 1) * 4 + hsel];
        if (t0 >= r0 && t0 < r1) {
            int s = se0 & 0xFFFF;
            uint2 p = *(const uint2*)(xw + ((size_t)(t0 - r0) * N + s) * 256 + lane * 4);
            ax += a0 * __uint_as_float(p.x << 16);
            ay += a0 * __uint_as_float(p.x & 0xFFFF0000u);
            az += a0 * __uint_as_float(p.y << 16);
            aw += a0 * __uint_as_float(p.y & 0xFFFF0000u);
        }
        if (t1 >= r0 && t1 < r1) {
            int s = se1 & 0xFFFF;
            uint2 p = *(const uint2*)(xw + ((size_t)(t1 - r0) * N + s) * 256 + lane * 4);
            ax += a1v * __uint_as_float(p.x << 16);
            ay += a1v * __uint_as_float(p.x & 0xFFFF0000u);
            az += a1v * __uint_as_float(p.y << 16);
            aw += a1v * __uint_as_float(p.y & 0xFFFF0000u);
        }
    }
    if (i < end) {
        int se = csr_se[i];
        int tt = se >> 16;
        if (tt >= r0 && tt < r1) {
            int s = se & 0xFFFF;
            float a = alpha_csr[i * 4 + hsel];
            uint2 p = *(const uint2*)(xw + ((size_t)(tt - r0) * N + s) * 256 + lane * 4);
            ax += a * __uint_as_float(p.x << 16);
            ay += a * __uint_as_float(p.x & 0xFFFF0000u);
            az += a * __uint_as_float(p.y << 16);
            aw += a * __uint_as_float(p.y & 0xFFFF0000u);
        }
    }
    float* o = out + (size_t)node * 256 + lane * 4;
    float vx, vy, vz, vw;
    if (first) {
        const float4 b = ((const float4*)bias)[lane];
        vx = ax + b.x; vy = ay + b.y; vz = az + b.z; vw = aw + b.w;
    } else {
        vx = o[0] + ax; vy = o[1] + ay; vz = o[2] + az; vw = o[3] + aw;
    }
    if (act) {
        vx = lrelu(vx, 0.01f); vy = lrelu(vy, 0.01f);
        vz = lrelu(vz, 0.01f); vw = lrelu(vw, 0.01f);
        unsigned short* xo = xbout + (size_t)node * 256 + lane * 4;
        xo[0] = f2bf(vx); xo[1] = f2bf(vy); xo[2] = f2bf(vz); xo[3] = f2bf(vw);
    }
    o[0] = vx; o[1] = vy; o[2] = vz; o[3] = vw;
}

extern "C" void kernel_launch(void* const* d_in, const int* in_sizes, int n_in,
                              void* d_out, int out_size, void* d_ws, size_t ws_size,
                              hipStream_t stream) {
    const float* kg   = (const float*)d_in[0];
    const float* cc0  = (const float*)d_in[1];
    const float* gw1  = (const float*)d_in[2];
    const float* gb1  = (const float*)d_in[3];
    const float* gw2  = (const float*)d_in[4];
    const float* gb2  = (const float*)d_in[5];
    const float* r1w  = (const float*)d_in[6];
    const float* r1q  = (const float*)d_in[7];
    const float* r1k  = (const float*)d_in[8];
    const float* r1b  = (const float*)d_in[9];
    const float* r2w  = (const float*)d_in[10];
    const float* r2q  = (const float*)d_in[11];
    const float* r2k  = (const float*)d_in[12];
    const float* r2b  = (const float*)d_in[13];
    const float* linw = (const float*)d_in[14];
    const float* linb = (const float*)d_in[15];
    const int*   ei   = (const int*)d_in[16];
    const int*   et   = (const int*)d_in[17];

    float* out = (float*)d_out;
    float* a1  = out + (size_t)N * C;
    float* a2  = a1 + (size_t)E * H;

    float* ws = (float*)d_ws;
    size_t off = 0;
    float* dis  = ws + off; off += N;
    float* h1   = ws + off; off += (size_t)N * 32;
    float* c1   = ws + off; off += (size_t)N * 32;
    unsigned short* h2b = (unsigned short*)(ws + off); off += (size_t)N * 64;
    float* x0   = ws + off; off += (size_t)N * C;
    float* hmid = ws + off; off += (size_t)N * C;
    float* qn   = ws + off; off += (size_t)N * R * H;
    float* kn   = ws + off; off += (size_t)N * R * H;
    float* wq   = ws + off; off += (size_t)R * 256 * H;
    float* wk   = ws + off; off += (size_t)R * 256 * H;
    int* cnt     = (int*)(ws + off); off += N;
    int* rowptr  = (int*)(ws + off); off += N + 1;
    int* cursor  = (int*)(ws + off); off += N;
    int* csr_se  = (int*)(ws + off); off += E;
    int* csr_eid = (int*)(ws + off); off += E;
    float* alpha = ws + off; off += (size_t)E * H;
    unsigned short* xb0 = (unsigned short*)(ws + off); off += (size_t)N * 128;
    unsigned short* xb1 = (unsigned short*)(ws + off); off += (size_t)N * 128;
    unsigned short* wt  = (unsigned short*)(ws + off); off += (size_t)R * 32768;
    unsigned short* wtl = (unsigned short*)(ws + off); off += 32768;
    unsigned short* wqkb = (unsigned short*)(ws + off); off += 8192;
    unsigned short* xwb = (unsigned short*)(ws + off);

    size_t fixedB = off * 4;
    int K = R;
    if (ws_size > fixedB) {
        size_t kmax = (ws_size - fixedB) / ((size_t)N * C * 2);
        if (kmax < (size_t)K) K = (int)kmax;
    } else {
        K = 1;
    }
    if (K < 1) K = 1;

    const int B = 256;
    auto cdiv = [](long a, long b) { return (int)((a + b - 1) / b); };
    const int MT = cdiv(N, TM);  // 157 m-tiles

    // ---- CSR build ----
    k_zero_int<<<cdiv(N, B), B, 0, stream>>>(cnt, N);
    k_count<<<cdiv(E, B), B, 0, stream>>>(ei, cnt);
    k_scan<<<1, 1024, 0, stream>>>(cnt, rowptr);
    k_dis<<<cdiv(N, B), B, 0, stream>>>(cnt, dis);
    k_copy_int<<<cdiv(N, B), B, 0, stream>>>(rowptr, cursor, N);
    k_scatter<<<cdiv(E, B), B, 0, stream>>>(ei, et, cursor, csr_se, csr_eid);

    // ---- GCN ----
    k_h1<<<cdiv((long)N * 32, B), B, 0, stream>>>(cc0, gw1, h1);
    k_agg32<<<cdiv((long)N * 32, B), B, 0, stream>>>(rowptr, csr_se, dis, h1, gb1, c1);
    k_h2<<<cdiv((long)N * 128, B), B, 0, stream>>>(c1, gw2, h2b);
    k_kgcopy<<<cdiv((long)N * 128, B), B, 0, stream>>>(kg, x0, xb0);
    k_agg128<<<cdiv((long)N * 128, B), B, 0, stream>>>(rowptr, csr_se, dis, h2b,
                                                       gb2, x0, xb0);

    auto rgat = [&](unsigned short* xb, const float* W,
                    const float* q, const float* kk, const float* b,
                    float* obuf, unsigned short* xbout, float* aout, int act) {
        k_wqk<<<cdiv((long)R * 256 * H, B), B, 0, stream>>>(W, q, kk, wq, wk);
        k_wqk_pack<<<cdiv((long)64 * 256, B), B, 0, stream>>>(wq, wk, wqkb);
        k_qnkn_mfma<<<cdiv(N, 64), B, 0, stream>>>(xb, wqkb, qn, kn);
        k_soft<<<cdiv((long)N * H, B), B, 0, stream>>>(rowptr, csr_se, csr_eid,
                                                       qn, kn, alpha, aout);
        k_wconv<<<cdiv((long)R * 65536, B), B, 0, stream>>>(W, wt, R);
        for (int r0 = 0; r0 < R; r0 += K) {
            int kc = (R - r0) < K ? (R - r0) : K;
            int gx = 8 * kc * (C / TN) * cdiv(MT, 8);
            gemm_mfma3<<<gx, 256, 0, stream>>>(xb, wt + ((size_t)r0 << 16), xwb,
                                               nullptr, nullptr, N, kc, C / TN, MT);
            int last = (r0 + kc >= R) ? 1 : 0;
            k_msg_gather<<<cdiv((long)N * 64, B), B, 0, stream>>>(
                rowptr, csr_se, alpha, xwb, b, obuf, xbout, r0, r0 + kc,
                r0 == 0 ? 1 : 0, act && last);
        }
    };

    rgat(xb0, r1w, r1q, r1k, r1b, hmid, xb1, a1, 1);
    rgat(xb1, r2w, r2q, r2k, r2b, out, nullptr, a2, 0);

    // out += x0 @ lin_w + lin_b   (bf16 MFMA, fp32 accumulate)
    k_wconv<<<cdiv((long)65536, B), B, 0, stream>>>(linw, wtl, 1);
    int gx = 8 * 1 * (C / TN) * cdiv(MT, 8);
    gemm_mfma3<<<gx, 256, 0, stream>>>(xb0, wtl, nullptr, out, linb, N, 1, C / TN, MT);
}